// Round 4
// baseline (1008.487 us; speedup 1.0000x reference)
//
#include <hip/hip_runtime.h>
#include <hip/hip_bf16.h>

#define N_NODES 50000
#define N_EDGES 800000

typedef short short8 __attribute__((ext_vector_type(8)));
typedef float floatx4 __attribute__((ext_vector_type(4)));
typedef unsigned short ushort4v __attribute__((ext_vector_type(4)));

// ---- bf16 helpers (RNE) ---------------------------------------------------
__device__ __forceinline__ unsigned short f2bf(float f) {
    unsigned u = __float_as_uint(f);
    unsigned r = (u + 0x7fff + ((u >> 16) & 1)) >> 16;
    return (unsigned short)r;
}
__device__ __forceinline__ float bf2f(unsigned short h) {
    return __uint_as_float(((unsigned)h) << 16);
}

// async global->LDS, 16B per lane; lds dest = wave-uniform base + lane*16
__device__ __forceinline__ void gload16(const void* gp, void* lp) {
    __builtin_amdgcn_global_load_lds(
        (const __attribute__((address_space(1))) unsigned int*)gp,
        (__attribute__((address_space(3))) unsigned int*)lp,
        16, 0, 0);
}

// ---------------------------------------------------------------------------
__global__ void k_init(int* __restrict__ cnt, float* __restrict__ g) {
    int i = blockIdx.x * blockDim.x + threadIdx.x;
    if (i < N_NODES) cnt[i] = 0;
    if (i < 256) g[i] = 0.0f;
}

__global__ void k_count(const int* __restrict__ col, int* __restrict__ cnt) {
    int e = blockIdx.x * blockDim.x + threadIdx.x;
    if (e < N_EDGES) atomicAdd(&cnt[col[e]], 1);
}

__global__ void k_dinv(const int* __restrict__ cnt, float* __restrict__ dinv) {
    int i = blockIdx.x * blockDim.x + threadIdx.x;
    if (i < N_NODES) dinv[i] = 1.0f / sqrtf((float)(cnt[i] + 1));
}

__global__ void k_scan(const int* __restrict__ cnt, int* __restrict__ off,
                       int* __restrict__ cursor) {
    const int T = 1024;
    const int CHUNK = (N_NODES + T - 1) / T; // 49
    __shared__ int part[T];
    int t = threadIdx.x;
    int lo = t * CHUNK;
    int hi = lo + CHUNK; if (hi > N_NODES) hi = N_NODES;
    int s = 0;
    for (int i = lo; i < hi; ++i) s += cnt[i];
    part[t] = s;
    __syncthreads();
    for (int d = 1; d < T; d <<= 1) {
        int v = 0;
        if (t >= d) v = part[t - d];
        __syncthreads();
        if (t >= d) part[t] += v;
        __syncthreads();
    }
    int run = part[t] - s;
    for (int i = lo; i < hi; ++i) {
        off[i] = run;
        cursor[i] = run;
        run += cnt[i];
    }
    if (t == T - 1) off[N_NODES] = run;
}

__global__ void k_fill(const int* __restrict__ row, const int* __restrict__ col,
                       const float* __restrict__ dinv, int* __restrict__ cursor,
                       int2* __restrict__ epack) {
    int e = blockIdx.x * blockDim.x + threadIdx.x;
    if (e >= N_EDGES) return;
    int v = col[e];
    int p = atomicAdd(&cursor[v], 1);
    int r = row[e];
    epack[p] = make_int2(r, __float_as_int(dinv[r]));
}

// convert W [K][N] fp32 -> transposed split bf16 WT{h,l} [N][K]
__global__ void k_prepW(const float* __restrict__ W,
                        unsigned short* __restrict__ Th,
                        unsigned short* __restrict__ Tl, int K, int N) {
    int idx = blockIdx.x * blockDim.x + threadIdx.x;
    if (idx >= K * N) return;
    int n = idx / K, k = idx - n * K;
    float v = W[(size_t)k * N + n];
    unsigned short h = f2bf(v);
    Th[idx] = h;
    Tl[idx] = f2bf(v - bf2f(h));
}

// aggregation: res[v] = dinv[v] * ( x[v]*dinv[v] + sum_j x[r_j]*dinv[r_j] )
// MODE 0: fp32 out + bias + relu
// MODE 1: split bf16 out (hi/lo)
// MODE 2: bias + relu + fused mean-pool into g (no activation written)
// Edge loop unrolled 4x with 4 independent accumulators (4 gathers in flight).
// Grids divide N_NODES exactly (50000 % 4 == 0, % 8 == 0) -> no range guard,
// safe block-level barrier in MODE 2.
template <int DIM, int MODE>
__global__ __launch_bounds__(256) void k_agg4(
    const float* __restrict__ x, const int* __restrict__ off,
    const int2* __restrict__ epack, const float* __restrict__ dinv,
    const float* __restrict__ bias, float* __restrict__ outf,
    unsigned short* __restrict__ outh, unsigned short* __restrict__ outl,
    float* __restrict__ g) {
    const int LPN = DIM / 4;
    const int NPB = 256 / LPN;
    __shared__ float gpart[256];
    if (MODE == 2) {
        gpart[threadIdx.x] = 0.0f;
        __syncthreads();
    }
    int v = blockIdx.x * NPB + threadIdx.x / LPN;
    int f = (threadIdx.x % LPN) * 4;
    float dv = dinv[v];
    const float* __restrict__ xf = x + f;
    float4 xv = *(const float4*)&xf[(size_t)v * DIM];
    float4 a0, a1, a2, a3;
    a0.x = xv.x * dv; a0.y = xv.y * dv; a0.z = xv.z * dv; a0.w = xv.w * dv;
    a1 = make_float4(0.f, 0.f, 0.f, 0.f);
    a2 = a1; a3 = a1;
    int s = off[v], e = off[v + 1];
    int j = s;
    for (; j + 4 <= e; j += 4) {
        int2 p0 = epack[j + 0];
        int2 p1 = epack[j + 1];
        int2 p2 = epack[j + 2];
        int2 p3 = epack[j + 3];
        float w0 = __int_as_float(p0.y);
        float w1 = __int_as_float(p1.y);
        float w2 = __int_as_float(p2.y);
        float w3 = __int_as_float(p3.y);
        float4 x0 = *(const float4*)&xf[(size_t)p0.x * DIM];
        float4 x1 = *(const float4*)&xf[(size_t)p1.x * DIM];
        float4 x2 = *(const float4*)&xf[(size_t)p2.x * DIM];
        float4 x3 = *(const float4*)&xf[(size_t)p3.x * DIM];
        a0.x += x0.x * w0; a0.y += x0.y * w0; a0.z += x0.z * w0; a0.w += x0.w * w0;
        a1.x += x1.x * w1; a1.y += x1.y * w1; a1.z += x1.z * w1; a1.w += x1.w * w1;
        a2.x += x2.x * w2; a2.y += x2.y * w2; a2.z += x2.z * w2; a2.w += x2.w * w2;
        a3.x += x3.x * w3; a3.y += x3.y * w3; a3.z += x3.z * w3; a3.w += x3.w * w3;
    }
    for (; j < e; ++j) {
        int2 p = epack[j];
        float w = __int_as_float(p.y);
        float4 xr = *(const float4*)&xf[(size_t)p.x * DIM];
        a0.x += xr.x * w; a0.y += xr.y * w; a0.z += xr.z * w; a0.w += xr.w * w;
    }
    float4 acc;
    acc.x = ((a0.x + a1.x) + (a2.x + a3.x)) * dv;
    acc.y = ((a0.y + a1.y) + (a2.y + a3.y)) * dv;
    acc.z = ((a0.z + a1.z) + (a2.z + a3.z)) * dv;
    acc.w = ((a0.w + a1.w) + (a2.w + a3.w)) * dv;
    size_t base = (size_t)v * DIM + f;
    if (MODE == 0) {
        float4 bv = *(const float4*)&bias[f];
        acc.x = fmaxf(acc.x + bv.x, 0.f);
        acc.y = fmaxf(acc.y + bv.y, 0.f);
        acc.z = fmaxf(acc.z + bv.z, 0.f);
        acc.w = fmaxf(acc.w + bv.w, 0.f);
        *(float4*)&outf[base] = acc;
    } else if (MODE == 1) {
        float a[4] = {acc.x, acc.y, acc.z, acc.w};
        ushort4v hv, lv;
#pragma unroll
        for (int i = 0; i < 4; ++i) {
            unsigned short h = f2bf(a[i]);
            hv[i] = h;
            lv[i] = f2bf(a[i] - bf2f(h));
        }
        *(ushort4v*)&outh[base] = hv;
        *(ushort4v*)&outl[base] = lv;
    } else {
        float4 bv = *(const float4*)&bias[f];
        acc.x = fmaxf(acc.x + bv.x, 0.f);
        acc.y = fmaxf(acc.y + bv.y, 0.f);
        acc.z = fmaxf(acc.z + bv.z, 0.f);
        acc.w = fmaxf(acc.w + bv.w, 0.f);
        atomicAdd(&gpart[f + 0], acc.x);
        atomicAdd(&gpart[f + 1], acc.y);
        atomicAdd(&gpart[f + 2], acc.z);
        atomicAdd(&gpart[f + 3], acc.w);
        __syncthreads();
        atomicAdd(&g[threadIdx.x], gpart[threadIdx.x]);
    }
}

// ---------------------------------------------------------------------------
// split-bf16 MFMA GEMM: C[M,N] = (Ah+Al)[M,K] @ (Bh+Bl)[K,N] (+bias)(relu)
// B pre-transposed [N][K]. 128x128 tile, BK=32, 4 waves, 4x4 frags 16x16x32.
// 3 MFMAs per frag pair (hh + hl + lh); fp32-equivalent accuracy.
template <int BIAS, int RELU, int SPLIT_OUT>
__global__ __launch_bounds__(256) void k_gemm_mfma(
    const unsigned short* __restrict__ Ah, const unsigned short* __restrict__ Al,
    const unsigned short* __restrict__ Bh, const unsigned short* __restrict__ Bl,
    const float* __restrict__ bias, float* __restrict__ Cf,
    unsigned short* __restrict__ Ch, unsigned short* __restrict__ Cl,
    int M, int K, int N) {
    __shared__ unsigned short AsH[128 * 32], AsL[128 * 32];
    __shared__ unsigned short BsH[128 * 32], BsL[128 * 32];
    int tid = threadIdx.x;
    int lane = tid & 63;
    int w = tid >> 6;
    int wr = w & 1, wc = w >> 1;
    int bm = blockIdx.x * 128, bn = blockIdx.y * 128;

    floatx4 acc[4][4];
    floatx4 zero = {0.f, 0.f, 0.f, 0.f};
#pragma unroll
    for (int t = 0; t < 4; ++t)
#pragma unroll
        for (int u = 0; u < 4; ++u) acc[t][u] = zero;

    int c0 = w * 2, c1 = c0 + 1;
    int srow = lane >> 2;
    int kc = (lane & 3) * 8;
    int ar0 = bm + c0 * 16 + srow; if (ar0 >= M) ar0 = M - 1;
    int ar1 = bm + c1 * 16 + srow; if (ar1 >= M) ar1 = M - 1;
    int br0 = bn + c0 * 16 + srow;
    int br1 = bn + c1 * 16 + srow;

    int fr = lane & 15;
    int fq = lane >> 4;

    for (int k0 = 0; k0 < K; k0 += 32) {
        __syncthreads();
        gload16(Ah + (size_t)ar0 * K + k0 + kc, AsH + c0 * 512);
        gload16(Ah + (size_t)ar1 * K + k0 + kc, AsH + c1 * 512);
        gload16(Al + (size_t)ar0 * K + k0 + kc, AsL + c0 * 512);
        gload16(Al + (size_t)ar1 * K + k0 + kc, AsL + c1 * 512);
        gload16(Bh + (size_t)br0 * K + k0 + kc, BsH + c0 * 512);
        gload16(Bh + (size_t)br1 * K + k0 + kc, BsH + c1 * 512);
        gload16(Bl + (size_t)br0 * K + k0 + kc, BsL + c0 * 512);
        gload16(Bl + (size_t)br1 * K + k0 + kc, BsL + c1 * 512);
        __syncthreads();

        short8 ah[4], al[4], bh[4], bl[4];
#pragma unroll
        for (int t = 0; t < 4; ++t) {
            int ra = (wr * 64 + t * 16 + fr) * 32 + fq * 8;
            ah[t] = *(const short8*)&AsH[ra];
            al[t] = *(const short8*)&AsL[ra];
            int rb = (wc * 64 + t * 16 + fr) * 32 + fq * 8;
            bh[t] = *(const short8*)&BsH[rb];
            bl[t] = *(const short8*)&BsL[rb];
        }
#pragma unroll
        for (int t = 0; t < 4; ++t)
#pragma unroll
            for (int u = 0; u < 4; ++u) {
                acc[t][u] = __builtin_amdgcn_mfma_f32_16x16x32_bf16(ah[t], bh[u], acc[t][u], 0, 0, 0);
                acc[t][u] = __builtin_amdgcn_mfma_f32_16x16x32_bf16(ah[t], bl[u], acc[t][u], 0, 0, 0);
                acc[t][u] = __builtin_amdgcn_mfma_f32_16x16x32_bf16(al[t], bh[u], acc[t][u], 0, 0, 0);
            }
    }

    // epilogue: C/D layout col = lane&15, row = (lane>>4)*4 + reg
#pragma unroll
    for (int u = 0; u < 4; ++u) {
        int colg = bn + wc * 64 + u * 16 + fr;
        float bv = BIAS ? bias[colg] : 0.0f;
#pragma unroll
        for (int t = 0; t < 4; ++t) {
#pragma unroll
            for (int r = 0; r < 4; ++r) {
                int rowg = bm + wr * 64 + t * 16 + fq * 4 + r;
                if (rowg < M) {
                    float o = acc[t][u][r] + bv;
                    if (RELU) o = fmaxf(o, 0.f);
                    size_t idx = (size_t)rowg * N + colg;
                    if (SPLIT_OUT) {
                        unsigned short h = f2bf(o);
                        Ch[idx] = h;
                        Cl[idx] = f2bf(o - bf2f(h));
                    } else {
                        Cf[idx] = o;
                    }
                }
            }
        }
    }
}

__global__ void k_mlp(const float* __restrict__ g,
                      const float* __restrict__ Wf1, const float* __restrict__ bf1,
                      const float* __restrict__ Wf2, const float* __restrict__ bf2,
                      const float* __restrict__ Wf3, const float* __restrict__ bf3,
                      float* __restrict__ out) {
    __shared__ float s0[256], s1[128], s2[64];
    int t = threadIdx.x;
    s0[t] = g[t] * (1.0f / (float)N_NODES);
    __syncthreads();
    if (t < 128) {
        float a = bf1[t];
        for (int k = 0; k < 256; ++k) a += s0[k] * Wf1[k * 128 + t];
        s1[t] = fmaxf(a, 0.0f);
    }
    __syncthreads();
    if (t < 64) {
        float a = bf2[t];
        for (int k = 0; k < 128; ++k) a += s1[k] * Wf2[k * 64 + t];
        s2[t] = fmaxf(a, 0.0f);
    }
    __syncthreads();
    if (t == 0) {
        float a = bf3[0];
        for (int k = 0; k < 64; ++k) a += s2[k] * Wf3[k];
        out[0] = a;
    }
}

extern "C" void kernel_launch(void* const* d_in, const int* in_sizes, int n_in,
                              void* d_out, int out_size, void* d_ws, size_t ws_size,
                              hipStream_t stream) {
    const float* x  = (const float*)d_in[0];
    const int* ei   = (const int*)d_in[1];
    const float* W1 = (const float*)d_in[2];
    const float* b1 = (const float*)d_in[3];
    const float* W2 = (const float*)d_in[4];
    const float* b2 = (const float*)d_in[5];
    const float* W3 = (const float*)d_in[6];
    const float* b3 = (const float*)d_in[7];
    const float* Wf1 = (const float*)d_in[8];
    const float* bf1 = (const float*)d_in[9];
    const float* Wf2 = (const float*)d_in[10];
    const float* bf2 = (const float*)d_in[11];
    const float* Wf3 = (const float*)d_in[12];
    const float* bf3 = (const float*)d_in[13];
    float* out = (float*)d_out;

    char* p = (char*)d_ws;
    auto alloc = [&](size_t bytes) {
        void* r = (void*)p;
        p += (bytes + 255) & ~((size_t)255);
        return r;
    };
    int*   cnt    = (int*)  alloc(N_NODES * sizeof(int));
    int*   off    = (int*)  alloc((N_NODES + 1) * sizeof(int));
    int*   cursor = (int*)  alloc(N_NODES * sizeof(int));
    float* dinv   = (float*)alloc(N_NODES * sizeof(float));
    int2*  epack  = (int2*) alloc((size_t)N_EDGES * sizeof(int2));
    float* g      = (float*)alloc(256 * sizeof(float));
    unsigned short* W1h = (unsigned short*)alloc(128 * 256 * 2);
    unsigned short* W1l = (unsigned short*)alloc(128 * 256 * 2);
    unsigned short* W2h = (unsigned short*)alloc(256 * 512 * 2);
    unsigned short* W2l = (unsigned short*)alloc(256 * 512 * 2);
    unsigned short* W3h = (unsigned short*)alloc(512 * 256 * 2);
    unsigned short* W3l = (unsigned short*)alloc(512 * 256 * 2);
    unsigned short* t0h = (unsigned short*)alloc((size_t)N_NODES * 128 * 2);
    unsigned short* t0l = (unsigned short*)alloc((size_t)N_NODES * 128 * 2);
    char* A2 = (char*)alloc((size_t)N_NODES * 512 * 2);  // h1 fp32 -> h2h bf16
    char* A3 = (char*)alloc((size_t)N_NODES * 256 * 4);  // t1h+t1l -> t2 fp32
    char* A4 = (char*)alloc((size_t)N_NODES * 512 * 2);  // h2l
    float* h1           = (float*)A2;
    unsigned short* h2h = (unsigned short*)A2;
    unsigned short* t1h = (unsigned short*)A3;
    unsigned short* t1l = (unsigned short*)(A3 + (size_t)N_NODES * 256 * 2);
    float* t2           = (float*)A3;
    unsigned short* h2l = (unsigned short*)A4;

    const int* row = ei;
    const int* col = ei + N_EDGES;

    const int NB = (N_NODES + 255) / 256;
    const int EB = (N_EDGES + 255) / 256;

    // CSR build + norm
    k_init<<<NB, 256, 0, stream>>>(cnt, g);
    k_count<<<EB, 256, 0, stream>>>(col, cnt);
    k_dinv<<<NB, 256, 0, stream>>>(cnt, dinv);
    k_scan<<<1, 1024, 0, stream>>>(cnt, off, cursor);
    k_fill<<<EB, 256, 0, stream>>>(row, col, dinv, cursor, epack);

    // weight prep (transpose + split)
    k_prepW<<<(128 * 256 + 255) / 256, 256, 0, stream>>>(W1, W1h, W1l, 128, 256);
    k_prepW<<<(256 * 512 + 255) / 256, 256, 0, stream>>>(W2, W2h, W2l, 256, 512);
    k_prepW<<<(512 * 256 + 255) / 256, 256, 0, stream>>>(W3, W3h, W3l, 512, 256);

    const int M = N_NODES;
    const int MB = (M + 127) / 128; // 391

    // conv1: t0 = agg(x) -> split; h1 = relu(t0@W1 + b1) fp32
    k_agg4<128, 1><<<N_NODES / 8, 256, 0, stream>>>(
        x, off, epack, dinv, nullptr, nullptr, t0h, t0l, nullptr);
    {
        dim3 grid(MB, 256 / 128);
        k_gemm_mfma<1, 1, 0><<<grid, 256, 0, stream>>>(
            t0h, t0l, W1h, W1l, b1, h1, nullptr, nullptr, M, 128, 256);
    }
    // conv2: t1 = agg(h1) -> split; h2 = relu(t1@W2 + b2) -> split
    k_agg4<256, 1><<<N_NODES / 4, 256, 0, stream>>>(
        h1, off, epack, dinv, nullptr, nullptr, t1h, t1l, nullptr);
    {
        dim3 grid(MB, 512 / 128);
        k_gemm_mfma<1, 1, 1><<<grid, 256, 0, stream>>>(
            t1h, t1l, W2h, W2l, b2, nullptr, h2h, h2l, M, 256, 512);
    }
    // conv3: t2 = h2@W3 fp32; fused agg + bias + relu + mean-pool into g
    {
        dim3 grid(MB, 256 / 128);
        k_gemm_mfma<0, 0, 0><<<grid, 256, 0, stream>>>(
            h2h, h2l, W3h, W3l, nullptr, t2, nullptr, nullptr, M, 512, 256);
    }
    k_agg4<256, 2><<<N_NODES / 4, 256, 0, stream>>>(
        t2, off, epack, dinv, b3, nullptr, nullptr, nullptr, g);

    // MLP
    k_mlp<<<1, 256, 0, stream>>>(g, Wf1, bf1, Wf2, bf2, Wf3, bf3, out);
}

// Round 5
// 818.324 us; speedup vs baseline: 1.2324x; 1.2324x over previous
//
#include <hip/hip_runtime.h>
#include <hip/hip_bf16.h>

#define N_NODES 50000
#define N_EDGES 800000
#define N_BUCKETS 64

typedef short short8 __attribute__((ext_vector_type(8)));
typedef float floatx4 __attribute__((ext_vector_type(4)));
typedef unsigned short ushort4v __attribute__((ext_vector_type(4)));

// ---- bf16 helpers (RNE) ---------------------------------------------------
__device__ __forceinline__ unsigned short f2bf(float f) {
    unsigned u = __float_as_uint(f);
    unsigned r = (u + 0x7fff + ((u >> 16) & 1)) >> 16;
    return (unsigned short)r;
}
__device__ __forceinline__ float bf2f(unsigned short h) {
    return __uint_as_float(((unsigned)h) << 16);
}

// async global->LDS, 16B per lane
__device__ __forceinline__ void gload16(const void* gp, void* lp) {
    __builtin_amdgcn_global_load_lds(
        (const __attribute__((address_space(1))) unsigned int*)gp,
        (__attribute__((address_space(3))) unsigned int*)lp,
        16, 0, 0);
}

// ---------------------------------------------------------------------------
__global__ void k_init(int* __restrict__ cnt, float* __restrict__ gb) {
    int i = blockIdx.x * blockDim.x + threadIdx.x;
    if (i < N_NODES) cnt[i] = 0;
    if (i < N_BUCKETS * 256) gb[i] = 0.0f;
}

__global__ void k_count(const int* __restrict__ col, int* __restrict__ cnt) {
    int e = blockIdx.x * blockDim.x + threadIdx.x;
    if (e < N_EDGES) atomicAdd(&cnt[col[e]], 1);
}

__global__ void k_dinv(const int* __restrict__ cnt, float* __restrict__ dinv) {
    int i = blockIdx.x * blockDim.x + threadIdx.x;
    if (i < N_NODES) dinv[i] = 1.0f / sqrtf((float)(cnt[i] + 1));
}

__global__ void k_scan(const int* __restrict__ cnt, int* __restrict__ off,
                       int* __restrict__ cursor) {
    const int T = 1024;
    const int CHUNK = (N_NODES + T - 1) / T; // 49
    __shared__ int part[T];
    int t = threadIdx.x;
    int lo = t * CHUNK;
    int hi = lo + CHUNK; if (hi > N_NODES) hi = N_NODES;
    int s = 0;
    for (int i = lo; i < hi; ++i) s += cnt[i];
    part[t] = s;
    __syncthreads();
    for (int d = 1; d < T; d <<= 1) {
        int v = 0;
        if (t >= d) v = part[t - d];
        __syncthreads();
        if (t >= d) part[t] += v;
        __syncthreads();
    }
    int run = part[t] - s;
    for (int i = lo; i < hi; ++i) {
        off[i] = run;
        cursor[i] = run;
        run += cnt[i];
    }
    if (t == T - 1) off[N_NODES] = run;
}

__global__ void k_fill(const int* __restrict__ row, const int* __restrict__ col,
                       const float* __restrict__ dinv, int* __restrict__ cursor,
                       int2* __restrict__ epack) {
    int e = blockIdx.x * blockDim.x + threadIdx.x;
    if (e >= N_EDGES) return;
    int v = col[e];
    int p = atomicAdd(&cursor[v], 1);
    int r = row[e];
    epack[p] = make_int2(r, __float_as_int(dinv[r]));
}

// convert W [K][N] fp32 -> transposed split bf16 WT{h,l} [N][K]
__global__ void k_prepW(const float* __restrict__ W,
                        unsigned short* __restrict__ Th,
                        unsigned short* __restrict__ Tl, int K, int N) {
    int idx = blockIdx.x * blockDim.x + threadIdx.x;
    if (idx >= K * N) return;
    int n = idx / K, k = idx - n * K;
    float v = W[(size_t)k * N + n];
    unsigned short h = f2bf(v);
    Th[idx] = h;
    Tl[idx] = f2bf(v - bf2f(h));
}

// aggregation: res[v] = dinv[v] * ( x[v]*dinv[v] + sum_j x[r_j]*dinv[r_j] )
// MODE 0: fp32 out + bias + relu
// MODE 1: split bf16 out (hi/lo)
// MODE 2: bias + relu + mean-pool partial into g_buckets[blockIdx%64][256]
// Edge loop: unroll 8, software-pipelined epack prefetch (next batch's edge
// descriptors load while current batch's 8 gathers are in flight).
template <int DIM, int MODE>
__global__ __launch_bounds__(256) void k_agg4(
    const float* __restrict__ x, const int* __restrict__ off,
    const int2* __restrict__ epack, const float* __restrict__ dinv,
    const float* __restrict__ bias, float* __restrict__ outf,
    unsigned short* __restrict__ outh, unsigned short* __restrict__ outl,
    float* __restrict__ gb) {
    const int LPN = DIM / 4;
    const int NPB = 256 / LPN;
    __shared__ float gpart[256];
    if (MODE == 2) {
        gpart[threadIdx.x] = 0.0f;
        __syncthreads();
    }
    int v = blockIdx.x * NPB + threadIdx.x / LPN;
    int f = (threadIdx.x % LPN) * 4;
    float dv = dinv[v];
    const float* __restrict__ xf = x + f;
    float4 xv = *(const float4*)&xf[(size_t)v * DIM];
    float4 a0, a1, a2, a3;
    a0.x = xv.x * dv; a0.y = xv.y * dv; a0.z = xv.z * dv; a0.w = xv.w * dv;
    a1 = make_float4(0.f, 0.f, 0.f, 0.f);
    a2 = a1; a3 = a1;
    int s = off[v], e = off[v + 1];
    int j = s;
    int2 pc0, pc1, pc2, pc3, pc4, pc5, pc6, pc7;
    if (j + 8 <= e) {
        pc0 = epack[j + 0]; pc1 = epack[j + 1];
        pc2 = epack[j + 2]; pc3 = epack[j + 3];
        pc4 = epack[j + 4]; pc5 = epack[j + 5];
        pc6 = epack[j + 6]; pc7 = epack[j + 7];
    }
    while (j + 8 <= e) {
        float w0 = __int_as_float(pc0.y), w1 = __int_as_float(pc1.y);
        float w2 = __int_as_float(pc2.y), w3 = __int_as_float(pc3.y);
        float w4 = __int_as_float(pc4.y), w5 = __int_as_float(pc5.y);
        float w6 = __int_as_float(pc6.y), w7 = __int_as_float(pc7.y);
        float4 x0 = *(const float4*)&xf[(size_t)pc0.x * DIM];
        float4 x1 = *(const float4*)&xf[(size_t)pc1.x * DIM];
        float4 x2 = *(const float4*)&xf[(size_t)pc2.x * DIM];
        float4 x3 = *(const float4*)&xf[(size_t)pc3.x * DIM];
        float4 x4 = *(const float4*)&xf[(size_t)pc4.x * DIM];
        float4 x5 = *(const float4*)&xf[(size_t)pc5.x * DIM];
        float4 x6 = *(const float4*)&xf[(size_t)pc6.x * DIM];
        float4 x7 = *(const float4*)&xf[(size_t)pc7.x * DIM];
        j += 8;
        if (j + 8 <= e) {  // prefetch next batch's descriptors
            pc0 = epack[j + 0]; pc1 = epack[j + 1];
            pc2 = epack[j + 2]; pc3 = epack[j + 3];
            pc4 = epack[j + 4]; pc5 = epack[j + 5];
            pc6 = epack[j + 6]; pc7 = epack[j + 7];
        }
        a0.x += x0.x * w0; a0.y += x0.y * w0; a0.z += x0.z * w0; a0.w += x0.w * w0;
        a1.x += x1.x * w1; a1.y += x1.y * w1; a1.z += x1.z * w1; a1.w += x1.w * w1;
        a2.x += x2.x * w2; a2.y += x2.y * w2; a2.z += x2.z * w2; a2.w += x2.w * w2;
        a3.x += x3.x * w3; a3.y += x3.y * w3; a3.z += x3.z * w3; a3.w += x3.w * w3;
        a0.x += x4.x * w4; a0.y += x4.y * w4; a0.z += x4.z * w4; a0.w += x4.w * w4;
        a1.x += x5.x * w5; a1.y += x5.y * w5; a1.z += x5.z * w5; a1.w += x5.w * w5;
        a2.x += x6.x * w6; a2.y += x6.y * w6; a2.z += x6.z * w6; a2.w += x6.w * w6;
        a3.x += x7.x * w7; a3.y += x7.y * w7; a3.z += x7.z * w7; a3.w += x7.w * w7;
    }
    for (; j < e; ++j) {
        int2 p = epack[j];
        float w = __int_as_float(p.y);
        float4 xr = *(const float4*)&xf[(size_t)p.x * DIM];
        a0.x += xr.x * w; a0.y += xr.y * w; a0.z += xr.z * w; a0.w += xr.w * w;
    }
    float4 acc;
    acc.x = ((a0.x + a1.x) + (a2.x + a3.x)) * dv;
    acc.y = ((a0.y + a1.y) + (a2.y + a3.y)) * dv;
    acc.z = ((a0.z + a1.z) + (a2.z + a3.z)) * dv;
    acc.w = ((a0.w + a1.w) + (a2.w + a3.w)) * dv;
    size_t base = (size_t)v * DIM + f;
    if (MODE == 0) {
        float4 bv = *(const float4*)&bias[f];
        acc.x = fmaxf(acc.x + bv.x, 0.f);
        acc.y = fmaxf(acc.y + bv.y, 0.f);
        acc.z = fmaxf(acc.z + bv.z, 0.f);
        acc.w = fmaxf(acc.w + bv.w, 0.f);
        *(float4*)&outf[base] = acc;
    } else if (MODE == 1) {
        float a[4] = {acc.x, acc.y, acc.z, acc.w};
        ushort4v hv, lv;
#pragma unroll
        for (int i = 0; i < 4; ++i) {
            unsigned short h = f2bf(a[i]);
            hv[i] = h;
            lv[i] = f2bf(a[i] - bf2f(h));
        }
        *(ushort4v*)&outh[base] = hv;
        *(ushort4v*)&outl[base] = lv;
    } else {
        float4 bv = *(const float4*)&bias[f];
        acc.x = fmaxf(acc.x + bv.x, 0.f);
        acc.y = fmaxf(acc.y + bv.y, 0.f);
        acc.z = fmaxf(acc.z + bv.z, 0.f);
        acc.w = fmaxf(acc.w + bv.w, 0.f);
        atomicAdd(&gpart[f + 0], acc.x);
        atomicAdd(&gpart[f + 1], acc.y);
        atomicAdd(&gpart[f + 2], acc.z);
        atomicAdd(&gpart[f + 3], acc.w);
        __syncthreads();
        // bucketed global accumulation: atomic depth ~= gridDim/64
        atomicAdd(&gb[(blockIdx.x & (N_BUCKETS - 1)) * 256 + threadIdx.x],
                  gpart[threadIdx.x]);
    }
}

// ---------------------------------------------------------------------------
// split-bf16 MFMA GEMM: C[M,N] = (Ah+Al)[M,K] @ (Bh+Bl)[K,N] (+bias)(relu)
// B pre-transposed [N][K]. 128x128 tile, BK=32, 4 waves, 4x4 frags 16x16x32.
// 3 MFMAs per frag pair (hh + hl + lh); fp32-equivalent accuracy.
template <int BIAS, int RELU, int SPLIT_OUT>
__global__ __launch_bounds__(256) void k_gemm_mfma(
    const unsigned short* __restrict__ Ah, const unsigned short* __restrict__ Al,
    const unsigned short* __restrict__ Bh, const unsigned short* __restrict__ Bl,
    const float* __restrict__ bias, float* __restrict__ Cf,
    unsigned short* __restrict__ Ch, unsigned short* __restrict__ Cl,
    int M, int K, int N) {
    __shared__ unsigned short AsH[128 * 32], AsL[128 * 32];
    __shared__ unsigned short BsH[128 * 32], BsL[128 * 32];
    int tid = threadIdx.x;
    int lane = tid & 63;
    int w = tid >> 6;
    int wr = w & 1, wc = w >> 1;
    int bm = blockIdx.x * 128, bn = blockIdx.y * 128;

    floatx4 acc[4][4];
    floatx4 zero = {0.f, 0.f, 0.f, 0.f};
#pragma unroll
    for (int t = 0; t < 4; ++t)
#pragma unroll
        for (int u = 0; u < 4; ++u) acc[t][u] = zero;

    int c0 = w * 2, c1 = c0 + 1;
    int srow = lane >> 2;
    int kc = (lane & 3) * 8;
    int ar0 = bm + c0 * 16 + srow; if (ar0 >= M) ar0 = M - 1;
    int ar1 = bm + c1 * 16 + srow; if (ar1 >= M) ar1 = M - 1;
    int br0 = bn + c0 * 16 + srow;
    int br1 = bn + c1 * 16 + srow;

    int fr = lane & 15;
    int fq = lane >> 4;

    for (int k0 = 0; k0 < K; k0 += 32) {
        __syncthreads();
        gload16(Ah + (size_t)ar0 * K + k0 + kc, AsH + c0 * 512);
        gload16(Ah + (size_t)ar1 * K + k0 + kc, AsH + c1 * 512);
        gload16(Al + (size_t)ar0 * K + k0 + kc, AsL + c0 * 512);
        gload16(Al + (size_t)ar1 * K + k0 + kc, AsL + c1 * 512);
        gload16(Bh + (size_t)br0 * K + k0 + kc, BsH + c0 * 512);
        gload16(Bh + (size_t)br1 * K + k0 + kc, BsH + c1 * 512);
        gload16(Bl + (size_t)br0 * K + k0 + kc, BsL + c0 * 512);
        gload16(Bl + (size_t)br1 * K + k0 + kc, BsL + c1 * 512);
        __syncthreads();

        short8 ah[4], al[4], bh[4], bl[4];
#pragma unroll
        for (int t = 0; t < 4; ++t) {
            int ra = (wr * 64 + t * 16 + fr) * 32 + fq * 8;
            ah[t] = *(const short8*)&AsH[ra];
            al[t] = *(const short8*)&AsL[ra];
            int rb = (wc * 64 + t * 16 + fr) * 32 + fq * 8;
            bh[t] = *(const short8*)&BsH[rb];
            bl[t] = *(const short8*)&BsL[rb];
        }
#pragma unroll
        for (int t = 0; t < 4; ++t)
#pragma unroll
            for (int u = 0; u < 4; ++u) {
                acc[t][u] = __builtin_amdgcn_mfma_f32_16x16x32_bf16(ah[t], bh[u], acc[t][u], 0, 0, 0);
                acc[t][u] = __builtin_amdgcn_mfma_f32_16x16x32_bf16(ah[t], bl[u], acc[t][u], 0, 0, 0);
                acc[t][u] = __builtin_amdgcn_mfma_f32_16x16x32_bf16(al[t], bh[u], acc[t][u], 0, 0, 0);
            }
    }

    // epilogue: C/D layout col = lane&15, row = (lane>>4)*4 + reg
#pragma unroll
    for (int u = 0; u < 4; ++u) {
        int colg = bn + wc * 64 + u * 16 + fr;
        float bv = BIAS ? bias[colg] : 0.0f;
#pragma unroll
        for (int t = 0; t < 4; ++t) {
#pragma unroll
            for (int r = 0; r < 4; ++r) {
                int rowg = bm + wr * 64 + t * 16 + fq * 4 + r;
                if (rowg < M) {
                    float o = acc[t][u][r] + bv;
                    if (RELU) o = fmaxf(o, 0.f);
                    size_t idx = (size_t)rowg * N + colg;
                    if (SPLIT_OUT) {
                        unsigned short h = f2bf(o);
                        Ch[idx] = h;
                        Cl[idx] = f2bf(o - bf2f(h));
                    } else {
                        Cf[idx] = o;
                    }
                }
            }
        }
    }
}

// tiny MLP; first reduces the 64 pool buckets
__global__ void k_mlp(const float* __restrict__ gb,
                      const float* __restrict__ Wf1, const float* __restrict__ bf1,
                      const float* __restrict__ Wf2, const float* __restrict__ bf2,
                      const float* __restrict__ Wf3, const float* __restrict__ bf3,
                      float* __restrict__ out) {
    __shared__ float s0[256], s1[128], s2[64];
    int t = threadIdx.x;
    float sum = 0.0f;
    for (int b = 0; b < N_BUCKETS; ++b) sum += gb[b * 256 + t];
    s0[t] = sum * (1.0f / (float)N_NODES);
    __syncthreads();
    if (t < 128) {
        float a = bf1[t];
        for (int k = 0; k < 256; ++k) a += s0[k] * Wf1[k * 128 + t];
        s1[t] = fmaxf(a, 0.0f);
    }
    __syncthreads();
    if (t < 64) {
        float a = bf2[t];
        for (int k = 0; k < 128; ++k) a += s1[k] * Wf2[k * 64 + t];
        s2[t] = fmaxf(a, 0.0f);
    }
    __syncthreads();
    if (t == 0) {
        float a = bf3[0];
        for (int k = 0; k < 64; ++k) a += s2[k] * Wf3[k];
        out[0] = a;
    }
}

extern "C" void kernel_launch(void* const* d_in, const int* in_sizes, int n_in,
                              void* d_out, int out_size, void* d_ws, size_t ws_size,
                              hipStream_t stream) {
    const float* x  = (const float*)d_in[0];
    const int* ei   = (const int*)d_in[1];
    const float* W1 = (const float*)d_in[2];
    const float* b1 = (const float*)d_in[3];
    const float* W2 = (const float*)d_in[4];
    const float* b2 = (const float*)d_in[5];
    const float* W3 = (const float*)d_in[6];
    const float* b3 = (const float*)d_in[7];
    const float* Wf1 = (const float*)d_in[8];
    const float* bf1 = (const float*)d_in[9];
    const float* Wf2 = (const float*)d_in[10];
    const float* bf2 = (const float*)d_in[11];
    const float* Wf3 = (const float*)d_in[12];
    const float* bf3 = (const float*)d_in[13];
    float* out = (float*)d_out;

    char* p = (char*)d_ws;
    auto alloc = [&](size_t bytes) {
        void* r = (void*)p;
        p += (bytes + 255) & ~((size_t)255);
        return r;
    };
    int*   cnt    = (int*)  alloc(N_NODES * sizeof(int));
    int*   off    = (int*)  alloc((N_NODES + 1) * sizeof(int));
    int*   cursor = (int*)  alloc(N_NODES * sizeof(int));
    float* dinv   = (float*)alloc(N_NODES * sizeof(float));
    int2*  epack  = (int2*) alloc((size_t)N_EDGES * sizeof(int2));
    float* gb     = (float*)alloc(N_BUCKETS * 256 * sizeof(float));
    unsigned short* W1h = (unsigned short*)alloc(128 * 256 * 2);
    unsigned short* W1l = (unsigned short*)alloc(128 * 256 * 2);
    unsigned short* W2h = (unsigned short*)alloc(256 * 512 * 2);
    unsigned short* W2l = (unsigned short*)alloc(256 * 512 * 2);
    unsigned short* W3h = (unsigned short*)alloc(512 * 256 * 2);
    unsigned short* W3l = (unsigned short*)alloc(512 * 256 * 2);
    unsigned short* t0h = (unsigned short*)alloc((size_t)N_NODES * 128 * 2);
    unsigned short* t0l = (unsigned short*)alloc((size_t)N_NODES * 128 * 2);
    char* A2 = (char*)alloc((size_t)N_NODES * 512 * 2);  // h1 fp32 -> h2h bf16
    char* A3 = (char*)alloc((size_t)N_NODES * 256 * 4);  // t1h+t1l -> t2 fp32
    char* A4 = (char*)alloc((size_t)N_NODES * 512 * 2);  // h2l
    float* h1           = (float*)A2;
    unsigned short* h2h = (unsigned short*)A2;
    unsigned short* t1h = (unsigned short*)A3;
    unsigned short* t1l = (unsigned short*)(A3 + (size_t)N_NODES * 256 * 2);
    float* t2           = (float*)A3;
    unsigned short* h2l = (unsigned short*)A4;

    const int* row = ei;
    const int* col = ei + N_EDGES;

    const int NB = (N_NODES + 255) / 256;
    const int EB = (N_EDGES + 255) / 256;

    // CSR build + norm
    k_init<<<NB, 256, 0, stream>>>(cnt, gb);
    k_count<<<EB, 256, 0, stream>>>(col, cnt);
    k_dinv<<<NB, 256, 0, stream>>>(cnt, dinv);
    k_scan<<<1, 1024, 0, stream>>>(cnt, off, cursor);
    k_fill<<<EB, 256, 0, stream>>>(row, col, dinv, cursor, epack);

    // weight prep (transpose + split)
    k_prepW<<<(128 * 256 + 255) / 256, 256, 0, stream>>>(W1, W1h, W1l, 128, 256);
    k_prepW<<<(256 * 512 + 255) / 256, 256, 0, stream>>>(W2, W2h, W2l, 256, 512);
    k_prepW<<<(512 * 256 + 255) / 256, 256, 0, stream>>>(W3, W3h, W3l, 512, 256);

    const int M = N_NODES;
    const int MB = (M + 127) / 128; // 391

    // conv1: t0 = agg(x) -> split; h1 = relu(t0@W1 + b1) fp32
    k_agg4<128, 1><<<N_NODES / 8, 256, 0, stream>>>(
        x, off, epack, dinv, nullptr, nullptr, t0h, t0l, nullptr);
    {
        dim3 grid(MB, 256 / 128);
        k_gemm_mfma<1, 1, 0><<<grid, 256, 0, stream>>>(
            t0h, t0l, W1h, W1l, b1, h1, nullptr, nullptr, M, 128, 256);
    }
    // conv2: t1 = agg(h1) -> split; h2 = relu(t1@W2 + b2) -> split
    k_agg4<256, 1><<<N_NODES / 4, 256, 0, stream>>>(
        h1, off, epack, dinv, nullptr, nullptr, t1h, t1l, nullptr);
    {
        dim3 grid(MB, 512 / 128);
        k_gemm_mfma<1, 1, 1><<<grid, 256, 0, stream>>>(
            t1h, t1l, W2h, W2l, b2, nullptr, h2h, h2l, M, 256, 512);
    }
    // conv3: t2 = h2@W3 fp32; fused agg + bias + relu + bucketed mean-pool
    {
        dim3 grid(MB, 256 / 128);
        k_gemm_mfma<0, 0, 0><<<grid, 256, 0, stream>>>(
            h2h, h2l, W3h, W3l, nullptr, t2, nullptr, nullptr, M, 512, 256);
    }
    k_agg4<256, 2><<<N_NODES / 4, 256, 0, stream>>>(
        t2, off, epack, dinv, b3, nullptr, nullptr, nullptr, gb);

    // MLP (reduces buckets internally)
    k_mlp<<<1, 256, 0, stream>>>(gb, Wf1, bf1, Wf2, bf2, Wf3, bf3, out);
}

// Round 6
// 642.964 us; speedup vs baseline: 1.5685x; 1.2727x over previous
//
#include <hip/hip_runtime.h>
#include <hip/hip_bf16.h>

#define N_NODES 50000
#define N_EDGES 800000
#define N_BUCKETS 64
#define M_PAD 50048  // 391 * 128, pads GEMM A-inputs so staging never reads OOB

typedef short short8 __attribute__((ext_vector_type(8)));
typedef float floatx4 __attribute__((ext_vector_type(4)));

// ---- bf16 helpers (RNE) ---------------------------------------------------
__device__ __forceinline__ unsigned short f2bf(float f) {
    unsigned u = __float_as_uint(f);
    unsigned r = (u + 0x7fff + ((u >> 16) & 1)) >> 16;
    return (unsigned short)r;
}
__device__ __forceinline__ float bf2f(unsigned short h) {
    return __uint_as_float(((unsigned)h) << 16);
}
__device__ __forceinline__ void expand2(unsigned u, float& lo, float& hi) {
    lo = __uint_as_float(u << 16);
    hi = __uint_as_float(u & 0xffff0000u);
}
__device__ __forceinline__ void accum8(float* a, uint4 g, float w) {
    float lo, hi;
    expand2(g.x, lo, hi); a[0] += lo * w; a[1] += hi * w;
    expand2(g.y, lo, hi); a[2] += lo * w; a[3] += hi * w;
    expand2(g.z, lo, hi); a[4] += lo * w; a[5] += hi * w;
    expand2(g.w, lo, hi); a[6] += lo * w; a[7] += hi * w;
}

// async global->LDS, 16B per lane; lds dest = wave-uniform base + lane*16
__device__ __forceinline__ void gload16(const void* gp, void* lp) {
    __builtin_amdgcn_global_load_lds(
        (const __attribute__((address_space(1))) unsigned int*)gp,
        (__attribute__((address_space(3))) unsigned int*)lp,
        16, 0, 0);
}

// ---------------------------------------------------------------------------
__global__ void k_init(int* __restrict__ cnt, float* __restrict__ gb) {
    int i = blockIdx.x * blockDim.x + threadIdx.x;
    if (i < N_NODES) cnt[i] = 0;
    if (i < N_BUCKETS * 256) gb[i] = 0.0f;
}

__global__ void k_count(const int* __restrict__ col, int* __restrict__ cnt) {
    int e = blockIdx.x * blockDim.x + threadIdx.x;
    if (e < N_EDGES) atomicAdd(&cnt[col[e]], 1);
}

__global__ void k_dinv(const int* __restrict__ cnt, float* __restrict__ dinv) {
    int i = blockIdx.x * blockDim.x + threadIdx.x;
    if (i < N_NODES) dinv[i] = 1.0f / sqrtf((float)(cnt[i] + 1));
}

__global__ void k_scan(const int* __restrict__ cnt, int* __restrict__ off,
                       int* __restrict__ cursor) {
    const int T = 1024;
    const int CHUNK = (N_NODES + T - 1) / T; // 49
    __shared__ int part[T];
    int t = threadIdx.x;
    int lo = t * CHUNK;
    int hi = lo + CHUNK; if (hi > N_NODES) hi = N_NODES;
    int s = 0;
    for (int i = lo; i < hi; ++i) s += cnt[i];
    part[t] = s;
    __syncthreads();
    for (int d = 1; d < T; d <<= 1) {
        int v = 0;
        if (t >= d) v = part[t - d];
        __syncthreads();
        if (t >= d) part[t] += v;
        __syncthreads();
    }
    int run = part[t] - s;
    for (int i = lo; i < hi; ++i) {
        off[i] = run;
        cursor[i] = run;
        run += cnt[i];
    }
    if (t == T - 1) off[N_NODES] = run;
}

__global__ void k_fill(const int* __restrict__ row, const int* __restrict__ col,
                       const float* __restrict__ dinv, int* __restrict__ cursor,
                       int2* __restrict__ epack) {
    int e = blockIdx.x * blockDim.x + threadIdx.x;
    if (e >= N_EDGES) return;
    int v = col[e];
    int p = atomicAdd(&cursor[v], 1);
    int r = row[e];
    epack[p] = make_int2(r, __float_as_int(dinv[r]));
}

// W [K][N] fp32 -> transposed split bf16 WT{h,l} [N][K] (weights stay exact)
__global__ void k_prepW(const float* __restrict__ W,
                        unsigned short* __restrict__ Th,
                        unsigned short* __restrict__ Tl, int K, int N) {
    int idx = blockIdx.x * blockDim.x + threadIdx.x;
    if (idx >= K * N) return;
    int n = idx / K, k = idx - n * K;
    float v = W[(size_t)k * N + n];
    unsigned short h = f2bf(v);
    Th[idx] = h;
    Tl[idx] = f2bf(v - bf2f(h));
}

// x fp32 -> bf16
__global__ void k_prepX(const float* __restrict__ x, unsigned short* __restrict__ xb) {
    int i = blockIdx.x * blockDim.x + threadIdx.x;
    if (i < N_NODES * 128) xb[i] = f2bf(x[i]);
}

// aggregation over bf16 rows, fp32 accum:
//   res[v] = dinv[v] * ( x[v]*dinv[v] + sum_j x[r_j]*dinv[r_j] )
// POOL=0: store bf16 row. POOL=1: bias+relu, bucketed mean-pool partial.
// Lanes: DIM/8 per node, 16B (8 feats) per lane. Edge loop unroll 4 (proven R3
// structure; R5's unroll-8+prefetch regressed occupancy 72->41%).
template <int DIM, int POOL>
__global__ __launch_bounds__(256) void k_aggb(
    const unsigned short* __restrict__ xb, const int* __restrict__ off,
    const int2* __restrict__ epack, const float* __restrict__ dinv,
    const float* __restrict__ bias, unsigned short* __restrict__ outb,
    float* __restrict__ gb) {
    const int LPN = DIM / 8;
    const int NPB = 256 / LPN;
    __shared__ float gpart[256];
    if (POOL) {
        gpart[threadIdx.x] = 0.0f;
        __syncthreads();
    }
    int v = blockIdx.x * NPB + threadIdx.x / LPN;   // grid divides N exactly
    int f = (threadIdx.x % LPN) * 8;
    float dv = dinv[v];
    const unsigned short* __restrict__ xf = xb + f;
    float a0[8], a1[8], a2[8], a3[8];
    {
        uint4 sv = *(const uint4*)&xf[(size_t)v * DIM];
        float e0, e1;
        expand2(sv.x, e0, e1); a0[0] = e0 * dv; a0[1] = e1 * dv;
        expand2(sv.y, e0, e1); a0[2] = e0 * dv; a0[3] = e1 * dv;
        expand2(sv.z, e0, e1); a0[4] = e0 * dv; a0[5] = e1 * dv;
        expand2(sv.w, e0, e1); a0[6] = e0 * dv; a0[7] = e1 * dv;
#pragma unroll
        for (int i = 0; i < 8; ++i) { a1[i] = 0.f; a2[i] = 0.f; a3[i] = 0.f; }
    }
    int s = off[v], e = off[v + 1];
    int j = s;
    for (; j + 4 <= e; j += 4) {
        int2 p0 = epack[j + 0];
        int2 p1 = epack[j + 1];
        int2 p2 = epack[j + 2];
        int2 p3 = epack[j + 3];
        uint4 g0 = *(const uint4*)&xf[(size_t)p0.x * DIM];
        uint4 g1 = *(const uint4*)&xf[(size_t)p1.x * DIM];
        uint4 g2 = *(const uint4*)&xf[(size_t)p2.x * DIM];
        uint4 g3 = *(const uint4*)&xf[(size_t)p3.x * DIM];
        accum8(a0, g0, __int_as_float(p0.y));
        accum8(a1, g1, __int_as_float(p1.y));
        accum8(a2, g2, __int_as_float(p2.y));
        accum8(a3, g3, __int_as_float(p3.y));
    }
    for (; j < e; ++j) {
        int2 p = epack[j];
        uint4 g = *(const uint4*)&xf[(size_t)p.x * DIM];
        accum8(a0, g, __int_as_float(p.y));
    }
    float acc[8];
#pragma unroll
    for (int i = 0; i < 8; ++i)
        acc[i] = ((a0[i] + a1[i]) + (a2[i] + a3[i])) * dv;
    if (!POOL) {
        uint4 o;
        o.x = (unsigned)f2bf(acc[0]) | ((unsigned)f2bf(acc[1]) << 16);
        o.y = (unsigned)f2bf(acc[2]) | ((unsigned)f2bf(acc[3]) << 16);
        o.z = (unsigned)f2bf(acc[4]) | ((unsigned)f2bf(acc[5]) << 16);
        o.w = (unsigned)f2bf(acc[6]) | ((unsigned)f2bf(acc[7]) << 16);
        *(uint4*)&outb[(size_t)v * DIM + f] = o;
    } else {
#pragma unroll
        for (int i = 0; i < 8; ++i) {
            float r = fmaxf(acc[i] + bias[f + i], 0.0f);
            atomicAdd(&gpart[f + i], r);
        }
        __syncthreads();
        atomicAdd(&gb[(blockIdx.x & (N_BUCKETS - 1)) * 256 + threadIdx.x],
                  gpart[threadIdx.x]);
    }
}

// ---------------------------------------------------------------------------
// bf16-A x split-bf16-B MFMA GEMM: C[M,N] = A[M,K] @ (Bh+Bl)[K,N] (+bias)(relu)
// B pre-transposed [N][K]. 128x128 tile, BK=32, double-buffered LDS (prefetch
// issued before compute so the pre-barrier vmcnt drain overlaps MFMAs).
// LDS k-chunks swizzled by (row>>1)&3 to break the 64B-row-stride conflicts.
template <int BIAS, int RELU>
__global__ __launch_bounds__(256) void k_gemm_b(
    const unsigned short* __restrict__ A,
    const unsigned short* __restrict__ Bh, const unsigned short* __restrict__ Bl,
    const float* __restrict__ bias, unsigned short* __restrict__ C,
    int M, int K, int N) {
    __shared__ unsigned short As[2][128 * 32];
    __shared__ unsigned short BsH[2][128 * 32];
    __shared__ unsigned short BsL[2][128 * 32];
    int tid = threadIdx.x;
    int lane = tid & 63;
    int w = tid >> 6;
    int wr = w & 1, wc = w >> 1;
    int bm = blockIdx.x * 128, bn = blockIdx.y * 128;

    floatx4 acc[4][4];
    floatx4 zero = {0.f, 0.f, 0.f, 0.f};
#pragma unroll
    for (int t = 0; t < 4; ++t)
#pragma unroll
        for (int u = 0; u < 4; ++u) acc[t][u] = zero;

    // staging: wave w stages chunks c0,c1 (16 rows x 32 k) of each tile.
    // lane l -> row l>>2 in chunk; LDS slot l&3 holds swizzled global k-chunk.
    int c0 = w * 2, c1 = c0 + 1;
    int srow = lane >> 2;
    int kg = ((lane & 3) - ((lane >> 3) & 3)) & 3;  // global k-chunk (inverse swizzle)
    int kc = kg * 8;
    const unsigned short* Ap0 = A + (size_t)(bm + c0 * 16 + srow) * K + kc;
    const unsigned short* Ap1 = A + (size_t)(bm + c1 * 16 + srow) * K + kc;
    const unsigned short* Bh0 = Bh + (size_t)(bn + c0 * 16 + srow) * K + kc;
    const unsigned short* Bh1 = Bh + (size_t)(bn + c1 * 16 + srow) * K + kc;
    const unsigned short* Bl0 = Bl + (size_t)(bn + c0 * 16 + srow) * K + kc;
    const unsigned short* Bl1 = Bl + (size_t)(bn + c1 * 16 + srow) * K + kc;

    const int KT = K >> 5;
#define STAGE(half, k0)                                   \
    do {                                                  \
        gload16(Ap0 + (k0), &As[half][c0 * 512]);         \
        gload16(Ap1 + (k0), &As[half][c1 * 512]);         \
        gload16(Bh0 + (k0), &BsH[half][c0 * 512]);        \
        gload16(Bh1 + (k0), &BsH[half][c1 * 512]);        \
        gload16(Bl0 + (k0), &BsL[half][c0 * 512]);        \
        gload16(Bl1 + (k0), &BsL[half][c1 * 512]);        \
    } while (0)

    STAGE(0, 0);
    __syncthreads();

    int fr = lane & 15;            // m (A) / n (B) within 16-tile
    int fq = lane >> 4;            // k-chunk 0..3
    int cl = ((fq + (fr >> 1)) & 3) * 8;  // swizzled LDS k-chunk offset

    for (int kt = 0; kt < KT; ++kt) {
        int half = kt & 1;
        if (kt + 1 < KT) STAGE(1 - half, (kt + 1) * 32);
        short8 av[4], bhv[4], blv[4];
#pragma unroll
        for (int t = 0; t < 4; ++t) {
            av[t]  = *(const short8*)&As[half][(wr * 64 + t * 16 + fr) * 32 + cl];
            bhv[t] = *(const short8*)&BsH[half][(wc * 64 + t * 16 + fr) * 32 + cl];
            blv[t] = *(const short8*)&BsL[half][(wc * 64 + t * 16 + fr) * 32 + cl];
        }
#pragma unroll
        for (int t = 0; t < 4; ++t)
#pragma unroll
            for (int u = 0; u < 4; ++u) {
                acc[t][u] = __builtin_amdgcn_mfma_f32_16x16x32_bf16(av[t], bhv[u], acc[t][u], 0, 0, 0);
                acc[t][u] = __builtin_amdgcn_mfma_f32_16x16x32_bf16(av[t], blv[u], acc[t][u], 0, 0, 0);
            }
        __syncthreads();
    }
#undef STAGE

    // epilogue: C/D layout col = lane&15, row = (lane>>4)*4 + reg
#pragma unroll
    for (int u = 0; u < 4; ++u) {
        int colg = bn + wc * 64 + u * 16 + fr;
        float bv = BIAS ? bias[colg] : 0.0f;
#pragma unroll
        for (int t = 0; t < 4; ++t) {
#pragma unroll
            for (int r = 0; r < 4; ++r) {
                int rowg = bm + wr * 64 + t * 16 + fq * 4 + r;
                if (rowg < M) {
                    float o = acc[t][u][r] + bv;
                    if (RELU) o = fmaxf(o, 0.f);
                    C[(size_t)rowg * N + colg] = f2bf(o);
                }
            }
        }
    }
}

// tiny MLP; first reduces the 64 pool buckets
__global__ void k_mlp(const float* __restrict__ gb,
                      const float* __restrict__ Wf1, const float* __restrict__ bf1,
                      const float* __restrict__ Wf2, const float* __restrict__ bf2,
                      const float* __restrict__ Wf3, const float* __restrict__ bf3,
                      float* __restrict__ out) {
    __shared__ float s0[256], s1[128], s2[64];
    int t = threadIdx.x;
    float sum = 0.0f;
    for (int b = 0; b < N_BUCKETS; ++b) sum += gb[b * 256 + t];
    s0[t] = sum * (1.0f / (float)N_NODES);
    __syncthreads();
    if (t < 128) {
        float a = bf1[t];
        for (int k = 0; k < 256; ++k) a += s0[k] * Wf1[k * 128 + t];
        s1[t] = fmaxf(a, 0.0f);
    }
    __syncthreads();
    if (t < 64) {
        float a = bf2[t];
        for (int k = 0; k < 128; ++k) a += s1[k] * Wf2[k * 64 + t];
        s2[t] = fmaxf(a, 0.0f);
    }
    __syncthreads();
    if (t == 0) {
        float a = bf3[0];
        for (int k = 0; k < 64; ++k) a += s2[k] * Wf3[k];
        out[0] = a;
    }
}

extern "C" void kernel_launch(void* const* d_in, const int* in_sizes, int n_in,
                              void* d_out, int out_size, void* d_ws, size_t ws_size,
                              hipStream_t stream) {
    const float* x  = (const float*)d_in[0];
    const int* ei   = (const int*)d_in[1];
    const float* W1 = (const float*)d_in[2];
    const float* b1 = (const float*)d_in[3];
    const float* W2 = (const float*)d_in[4];
    const float* b2 = (const float*)d_in[5];
    const float* W3 = (const float*)d_in[6];
    const float* b3 = (const float*)d_in[7];
    const float* Wf1 = (const float*)d_in[8];
    const float* bf1 = (const float*)d_in[9];
    const float* Wf2 = (const float*)d_in[10];
    const float* bf2 = (const float*)d_in[11];
    const float* Wf3 = (const float*)d_in[12];
    const float* bf3 = (const float*)d_in[13];
    float* out = (float*)d_out;

    char* p = (char*)d_ws;
    auto alloc = [&](size_t bytes) {
        void* r = (void*)p;
        p += (bytes + 255) & ~((size_t)255);
        return r;
    };
    int*   cnt    = (int*)  alloc(N_NODES * sizeof(int));
    int*   off    = (int*)  alloc((N_NODES + 1) * sizeof(int));
    int*   cursor = (int*)  alloc(N_NODES * sizeof(int));
    float* dinv   = (float*)alloc(N_NODES * sizeof(float));
    int2*  epack  = (int2*) alloc((size_t)N_EDGES * sizeof(int2));
    float* gb     = (float*)alloc(N_BUCKETS * 256 * sizeof(float));
    unsigned short* W1h = (unsigned short*)alloc(128 * 256 * 2);
    unsigned short* W1l = (unsigned short*)alloc(128 * 256 * 2);
    unsigned short* W2h = (unsigned short*)alloc(256 * 512 * 2);
    unsigned short* W2l = (unsigned short*)alloc(256 * 512 * 2);
    unsigned short* W3h = (unsigned short*)alloc(512 * 256 * 2);
    unsigned short* W3l = (unsigned short*)alloc(512 * 256 * 2);
    unsigned short* xb = (unsigned short*)alloc((size_t)N_NODES * 128 * 2);
    unsigned short* t0 = (unsigned short*)alloc((size_t)M_PAD * 128 * 2);
    unsigned short* h1 = (unsigned short*)alloc((size_t)N_NODES * 256 * 2);
    unsigned short* t1 = (unsigned short*)alloc((size_t)M_PAD * 256 * 2);
    unsigned short* h2 = (unsigned short*)alloc((size_t)M_PAD * 512 * 2);
    unsigned short* t2 = (unsigned short*)alloc((size_t)N_NODES * 256 * 2);

    const int* row = ei;
    const int* col = ei + N_EDGES;

    const int NB = (N_NODES + 255) / 256;
    const int EB = (N_EDGES + 255) / 256;

    // CSR build + norm
    k_init<<<NB, 256, 0, stream>>>(cnt, gb);
    k_count<<<EB, 256, 0, stream>>>(col, cnt);
    k_dinv<<<NB, 256, 0, stream>>>(cnt, dinv);
    k_scan<<<1, 1024, 0, stream>>>(cnt, off, cursor);
    k_fill<<<EB, 256, 0, stream>>>(row, col, dinv, cursor, epack);

    // weight prep (transpose + exact split) and x -> bf16
    k_prepW<<<(128 * 256 + 255) / 256, 256, 0, stream>>>(W1, W1h, W1l, 128, 256);
    k_prepW<<<(256 * 512 + 255) / 256, 256, 0, stream>>>(W2, W2h, W2l, 256, 512);
    k_prepW<<<(512 * 256 + 255) / 256, 256, 0, stream>>>(W3, W3h, W3l, 512, 256);
    k_prepX<<<(N_NODES * 128 + 255) / 256, 256, 0, stream>>>(x, xb);

    const int M = N_NODES;
    const int MB = (M + 127) / 128; // 391

    // conv1: t0 = agg(xb); h1 = relu(t0@W1 + b1)
    k_aggb<128, 0><<<N_NODES / 16, 256, 0, stream>>>(
        xb, off, epack, dinv, nullptr, t0, nullptr);
    {
        dim3 grid(MB, 256 / 128);
        k_gemm_b<1, 1><<<grid, 256, 0, stream>>>(t0, W1h, W1l, b1, h1, M, 128, 256);
    }
    // conv2: t1 = agg(h1); h2 = relu(t1@W2 + b2)
    k_aggb<256, 0><<<N_NODES / 8, 256, 0, stream>>>(
        h1, off, epack, dinv, nullptr, t1, nullptr);
    {
        dim3 grid(MB, 512 / 128);
        k_gemm_b<1, 1><<<grid, 256, 0, stream>>>(t1, W2h, W2l, b2, h2, M, 256, 512);
    }
    // conv3: t2 = h2@W3; fused agg + bias + relu + bucketed mean-pool
    {
        dim3 grid(MB, 256 / 128);
        k_gemm_b<0, 0><<<grid, 256, 0, stream>>>(h2, W3h, W3l, nullptr, t2, M, 512, 256);
    }
    k_aggb<256, 1><<<N_NODES / 8, 256, 0, stream>>>(
        t2, off, epack, dinv, b3, nullptr, gb);

    // MLP (reduces buckets internally)
    k_mlp<<<1, 256, 0, stream>>>(gb, Wf1, bf1, Wf2, bf2, Wf3, bf3, out);
}

// Round 7
// 532.658 us; speedup vs baseline: 1.8933x; 1.2071x over previous
//
#include <hip/hip_runtime.h>
#include <hip/hip_bf16.h>

#define N_NODES 50000
#define N_EDGES 800000
#define N_BUCKETS 64
#define M_PAD 50048  // 391 * 128, pads GEMM A-inputs so staging never reads OOB
#define SCAN_NB 196  // ceil(50000 / 256)

typedef short short8 __attribute__((ext_vector_type(8)));
typedef float floatx4 __attribute__((ext_vector_type(4)));

// ---- bf16 helpers (RNE) ---------------------------------------------------
__device__ __forceinline__ unsigned short f2bf(float f) {
    unsigned u = __float_as_uint(f);
    unsigned r = (u + 0x7fff + ((u >> 16) & 1)) >> 16;
    return (unsigned short)r;
}
__device__ __forceinline__ float bf2f(unsigned short h) {
    return __uint_as_float(((unsigned)h) << 16);
}
__device__ __forceinline__ void expand2(unsigned u, float& lo, float& hi) {
    lo = __uint_as_float(u << 16);
    hi = __uint_as_float(u & 0xffff0000u);
}
__device__ __forceinline__ void accum8(float* a, uint4 g, float w) {
    float lo, hi;
    expand2(g.x, lo, hi); a[0] += lo * w; a[1] += hi * w;
    expand2(g.y, lo, hi); a[2] += lo * w; a[3] += hi * w;
    expand2(g.z, lo, hi); a[4] += lo * w; a[5] += hi * w;
    expand2(g.w, lo, hi); a[6] += lo * w; a[7] += hi * w;
}

// async global->LDS, 16B per lane; lds dest = wave-uniform base + lane*16
__device__ __forceinline__ void gload16(const void* gp, void* lp) {
    __builtin_amdgcn_global_load_lds(
        (const __attribute__((address_space(1))) unsigned int*)gp,
        (__attribute__((address_space(3))) unsigned int*)lp,
        16, 0, 0);
}

// ---------------------------------------------------------------------------
__global__ void k_init(int* __restrict__ cnt, float* __restrict__ gb) {
    int i = blockIdx.x * blockDim.x + threadIdx.x;
    if (i < N_NODES) cnt[i] = 0;
    if (i < N_BUCKETS * 256) gb[i] = 0.0f;
}

__global__ void k_count(const int* __restrict__ col, int* __restrict__ cnt) {
    int e = blockIdx.x * blockDim.x + threadIdx.x;
    if (e < N_EDGES) atomicAdd(&cnt[col[e]], 1);
}

// --- 3-phase hierarchical exclusive scan of cnt -> off/cursor --------------
// A: per-block sums
__global__ __launch_bounds__(256) void k_scanA(const int* __restrict__ cnt,
                                               int* __restrict__ bsum) {
    __shared__ int red[256];
    int t = threadIdx.x;
    int i = blockIdx.x * 256 + t;
    red[t] = (i < N_NODES) ? cnt[i] : 0;
    __syncthreads();
    for (int d = 128; d > 0; d >>= 1) {
        if (t < d) red[t] += red[t + d];
        __syncthreads();
    }
    if (t == 0) bsum[blockIdx.x] = red[0];
}

// B: exclusive scan of the block sums (single block)
__global__ __launch_bounds__(256) void k_scanB(const int* __restrict__ bsum,
                                               int* __restrict__ bbase,
                                               int* __restrict__ off) {
    __shared__ int sc[256];
    int t = threadIdx.x;
    sc[t] = (t < SCAN_NB) ? bsum[t] : 0;
    __syncthreads();
    for (int d = 1; d < 256; d <<= 1) {
        int v = 0;
        if (t >= d) v = sc[t - d];
        __syncthreads();
        if (t >= d) sc[t] += v;
        __syncthreads();
    }
    if (t < SCAN_NB) bbase[t] = sc[t] - bsum[t];  // exclusive
    if (t == 0) off[N_NODES] = N_EDGES + N_NODES; // total incl. self-loop? no:
    // cnt holds edge-only in-degree; off spans edges only.
    if (t == 0) off[N_NODES] = N_EDGES;
}

// C: per-block exclusive scan + base; writes off, cursor, dinv
__global__ __launch_bounds__(256) void k_scanC(const int* __restrict__ cnt,
                                               const int* __restrict__ bbase,
                                               int* __restrict__ off,
                                               int* __restrict__ cursor,
                                               float* __restrict__ dinv) {
    __shared__ int sc[256];
    int t = threadIdx.x;
    int i = blockIdx.x * 256 + t;
    int c = (i < N_NODES) ? cnt[i] : 0;
    sc[t] = c;
    __syncthreads();
    for (int d = 1; d < 256; d <<= 1) {
        int v = 0;
        if (t >= d) v = sc[t - d];
        __syncthreads();
        if (t >= d) sc[t] += v;
        __syncthreads();
    }
    if (i < N_NODES) {
        int excl = sc[t] - c + bbase[blockIdx.x];
        off[i] = excl;
        cursor[i] = excl;
        dinv[i] = 1.0f / sqrtf((float)(c + 1));
    }
}

__global__ void k_fill(const int* __restrict__ row, const int* __restrict__ col,
                       const float* __restrict__ dinv, int* __restrict__ cursor,
                       int2* __restrict__ epack) {
    int e = blockIdx.x * blockDim.x + threadIdx.x;
    if (e >= N_EDGES) return;
    int v = col[e];
    int p = atomicAdd(&cursor[v], 1);
    int r = row[e];
    epack[p] = make_int2(r, __float_as_int(dinv[r]));
}

// W [K][N] fp32 -> transposed split bf16 WT{h,l} [N][K] (weights stay exact)
__global__ void k_prepW(const float* __restrict__ W,
                        unsigned short* __restrict__ Th,
                        unsigned short* __restrict__ Tl, int K, int N) {
    int idx = blockIdx.x * blockDim.x + threadIdx.x;
    if (idx >= K * N) return;
    int n = idx / K, k = idx - n * K;
    float v = W[(size_t)k * N + n];
    unsigned short h = f2bf(v);
    Th[idx] = h;
    Tl[idx] = f2bf(v - bf2f(h));
}

// x fp32 -> bf16
__global__ void k_prepX(const float* __restrict__ x, unsigned short* __restrict__ xb) {
    int i = blockIdx.x * blockDim.x + threadIdx.x;
    if (i < N_NODES * 128) xb[i] = f2bf(x[i]);
}

// aggregation over bf16 rows, fp32 accum:
//   res[v] = dinv[v] * ( x[v]*dinv[v] + sum_j x[r_j]*dinv[r_j] )
// POOL=0: store bf16 row. POOL=1: bias+relu, bucketed mean-pool partial.
// Lanes: DIM/8 per node, 16B (8 feats) per lane. Edge loop unroll 4 (proven R3
// structure; R5's unroll-8+prefetch regressed occupancy 72->41%).
template <int DIM, int POOL>
__global__ __launch_bounds__(256) void k_aggb(
    const unsigned short* __restrict__ xb, const int* __restrict__ off,
    const int2* __restrict__ epack, const float* __restrict__ dinv,
    const float* __restrict__ bias, unsigned short* __restrict__ outb,
    float* __restrict__ gb) {
    const int LPN = DIM / 8;
    const int NPB = 256 / LPN;
    __shared__ float gpart[256];
    if (POOL) {
        gpart[threadIdx.x] = 0.0f;
        __syncthreads();
    }
    int v = blockIdx.x * NPB + threadIdx.x / LPN;   // grid divides N exactly
    int f = (threadIdx.x % LPN) * 8;
    float dv = dinv[v];
    const unsigned short* __restrict__ xf = xb + f;
    float a0[8], a1[8], a2[8], a3[8];
    {
        uint4 sv = *(const uint4*)&xf[(size_t)v * DIM];
        float e0, e1;
        expand2(sv.x, e0, e1); a0[0] = e0 * dv; a0[1] = e1 * dv;
        expand2(sv.y, e0, e1); a0[2] = e0 * dv; a0[3] = e1 * dv;
        expand2(sv.z, e0, e1); a0[4] = e0 * dv; a0[5] = e1 * dv;
        expand2(sv.w, e0, e1); a0[6] = e0 * dv; a0[7] = e1 * dv;
#pragma unroll
        for (int i = 0; i < 8; ++i) { a1[i] = 0.f; a2[i] = 0.f; a3[i] = 0.f; }
    }
    int s = off[v], e = off[v + 1];
    int j = s;
    for (; j + 4 <= e; j += 4) {
        int2 p0 = epack[j + 0];
        int2 p1 = epack[j + 1];
        int2 p2 = epack[j + 2];
        int2 p3 = epack[j + 3];
        uint4 g0 = *(const uint4*)&xf[(size_t)p0.x * DIM];
        uint4 g1 = *(const uint4*)&xf[(size_t)p1.x * DIM];
        uint4 g2 = *(const uint4*)&xf[(size_t)p2.x * DIM];
        uint4 g3 = *(const uint4*)&xf[(size_t)p3.x * DIM];
        accum8(a0, g0, __int_as_float(p0.y));
        accum8(a1, g1, __int_as_float(p1.y));
        accum8(a2, g2, __int_as_float(p2.y));
        accum8(a3, g3, __int_as_float(p3.y));
    }
    for (; j < e; ++j) {
        int2 p = epack[j];
        uint4 g = *(const uint4*)&xf[(size_t)p.x * DIM];
        accum8(a0, g, __int_as_float(p.y));
    }
    float acc[8];
#pragma unroll
    for (int i = 0; i < 8; ++i)
        acc[i] = ((a0[i] + a1[i]) + (a2[i] + a3[i])) * dv;
    if (!POOL) {
        uint4 o;
        o.x = (unsigned)f2bf(acc[0]) | ((unsigned)f2bf(acc[1]) << 16);
        o.y = (unsigned)f2bf(acc[2]) | ((unsigned)f2bf(acc[3]) << 16);
        o.z = (unsigned)f2bf(acc[4]) | ((unsigned)f2bf(acc[5]) << 16);
        o.w = (unsigned)f2bf(acc[6]) | ((unsigned)f2bf(acc[7]) << 16);
        *(uint4*)&outb[(size_t)v * DIM + f] = o;
    } else {
#pragma unroll
        for (int i = 0; i < 8; ++i) {
            float r = fmaxf(acc[i] + bias[f + i], 0.0f);
            atomicAdd(&gpart[f + i], r);
        }
        __syncthreads();
        atomicAdd(&gb[(blockIdx.x & (N_BUCKETS - 1)) * 256 + threadIdx.x],
                  gpart[threadIdx.x]);
    }
}

// ---------------------------------------------------------------------------
// bf16-A x split-bf16-B MFMA GEMM: C[M,N] = A[M,K] @ (Bh+Bl)[K,N] (+bias)(relu)
// B pre-transposed [N][K]. 128x128 tile, BK=32, double-buffered LDS (prefetch
// issued before compute so the pre-barrier vmcnt drain overlaps MFMAs).
// LDS k-chunks swizzled by (row>>1)&3 to break the 64B-row-stride conflicts.
template <int BIAS, int RELU>
__global__ __launch_bounds__(256) void k_gemm_b(
    const unsigned short* __restrict__ A,
    const unsigned short* __restrict__ Bh, const unsigned short* __restrict__ Bl,
    const float* __restrict__ bias, unsigned short* __restrict__ C,
    int M, int K, int N) {
    __shared__ unsigned short As[2][128 * 32];
    __shared__ unsigned short BsH[2][128 * 32];
    __shared__ unsigned short BsL[2][128 * 32];
    int tid = threadIdx.x;
    int lane = tid & 63;
    int w = tid >> 6;
    int wr = w & 1, wc = w >> 1;
    int bm = blockIdx.x * 128, bn = blockIdx.y * 128;

    floatx4 acc[4][4];
    floatx4 zero = {0.f, 0.f, 0.f, 0.f};
#pragma unroll
    for (int t = 0; t < 4; ++t)
#pragma unroll
        for (int u = 0; u < 4; ++u) acc[t][u] = zero;

    int c0 = w * 2, c1 = c0 + 1;
    int srow = lane >> 2;
    int kg = ((lane & 3) - ((lane >> 3) & 3)) & 3;  // global k-chunk (inverse swizzle)
    int kc = kg * 8;
    const unsigned short* Ap0 = A + (size_t)(bm + c0 * 16 + srow) * K + kc;
    const unsigned short* Ap1 = A + (size_t)(bm + c1 * 16 + srow) * K + kc;
    const unsigned short* Bh0 = Bh + (size_t)(bn + c0 * 16 + srow) * K + kc;
    const unsigned short* Bh1 = Bh + (size_t)(bn + c1 * 16 + srow) * K + kc;
    const unsigned short* Bl0 = Bl + (size_t)(bn + c0 * 16 + srow) * K + kc;
    const unsigned short* Bl1 = Bl + (size_t)(bn + c1 * 16 + srow) * K + kc;

    const int KT = K >> 5;
#define STAGE(half, k0)                                   \
    do {                                                  \
        gload16(Ap0 + (k0), &As[half][c0 * 512]);         \
        gload16(Ap1 + (k0), &As[half][c1 * 512]);         \
        gload16(Bh0 + (k0), &BsH[half][c0 * 512]);        \
        gload16(Bh1 + (k0), &BsH[half][c1 * 512]);        \
        gload16(Bl0 + (k0), &BsL[half][c0 * 512]);        \
        gload16(Bl1 + (k0), &BsL[half][c1 * 512]);        \
    } while (0)

    STAGE(0, 0);
    __syncthreads();

    int fr = lane & 15;            // m (A) / n (B) within 16-tile
    int fq = lane >> 4;            // k-chunk 0..3
    int cl = ((fq + (fr >> 1)) & 3) * 8;  // swizzled LDS k-chunk offset

    for (int kt = 0; kt < KT; ++kt) {
        int half = kt & 1;
        if (kt + 1 < KT) STAGE(1 - half, (kt + 1) * 32);
        short8 av[4], bhv[4], blv[4];
#pragma unroll
        for (int t = 0; t < 4; ++t) {
            av[t]  = *(const short8*)&As[half][(wr * 64 + t * 16 + fr) * 32 + cl];
            bhv[t] = *(const short8*)&BsH[half][(wc * 64 + t * 16 + fr) * 32 + cl];
            blv[t] = *(const short8*)&BsL[half][(wc * 64 + t * 16 + fr) * 32 + cl];
        }
#pragma unroll
        for (int t = 0; t < 4; ++t)
#pragma unroll
            for (int u = 0; u < 4; ++u) {
                acc[t][u] = __builtin_amdgcn_mfma_f32_16x16x32_bf16(av[t], bhv[u], acc[t][u], 0, 0, 0);
                acc[t][u] = __builtin_amdgcn_mfma_f32_16x16x32_bf16(av[t], blv[u], acc[t][u], 0, 0, 0);
            }
        __syncthreads();
    }
#undef STAGE

    // epilogue: C/D layout col = lane&15, row = (lane>>4)*4 + reg
#pragma unroll
    for (int u = 0; u < 4; ++u) {
        int colg = bn + wc * 64 + u * 16 + fr;
        float bv = BIAS ? bias[colg] : 0.0f;
#pragma unroll
        for (int t = 0; t < 4; ++t) {
#pragma unroll
            for (int r = 0; r < 4; ++r) {
                int rowg = bm + wr * 64 + t * 16 + fq * 4 + r;
                if (rowg < M) {
                    float o = acc[t][u][r] + bv;
                    if (RELU) o = fmaxf(o, 0.f);
                    C[(size_t)rowg * N + colg] = f2bf(o);
                }
            }
        }
    }
}

// tiny MLP; first reduces the 64 pool buckets
__global__ void k_mlp(const float* __restrict__ gb,
                      const float* __restrict__ Wf1, const float* __restrict__ bf1,
                      const float* __restrict__ Wf2, const float* __restrict__ bf2,
                      const float* __restrict__ Wf3, const float* __restrict__ bf3,
                      float* __restrict__ out) {
    __shared__ float s0[256], s1[128], s2[64];
    int t = threadIdx.x;
    float sum = 0.0f;
    for (int b = 0; b < N_BUCKETS; ++b) sum += gb[b * 256 + t];
    s0[t] = sum * (1.0f / (float)N_NODES);
    __syncthreads();
    if (t < 128) {
        float a = bf1[t];
        for (int k = 0; k < 256; ++k) a += s0[k] * Wf1[k * 128 + t];
        s1[t] = fmaxf(a, 0.0f);
    }
    __syncthreads();
    if (t < 64) {
        float a = bf2[t];
        for (int k = 0; k < 128; ++k) a += s1[k] * Wf2[k * 64 + t];
        s2[t] = fmaxf(a, 0.0f);
    }
    __syncthreads();
    if (t == 0) {
        float a = bf3[0];
        for (int k = 0; k < 64; ++k) a += s2[k] * Wf3[k];
        out[0] = a;
    }
}

extern "C" void kernel_launch(void* const* d_in, const int* in_sizes, int n_in,
                              void* d_out, int out_size, void* d_ws, size_t ws_size,
                              hipStream_t stream) {
    const float* x  = (const float*)d_in[0];
    const int* ei   = (const int*)d_in[1];
    const float* W1 = (const float*)d_in[2];
    const float* b1 = (const float*)d_in[3];
    const float* W2 = (const float*)d_in[4];
    const float* b2 = (const float*)d_in[5];
    const float* W3 = (const float*)d_in[6];
    const float* b3 = (const float*)d_in[7];
    const float* Wf1 = (const float*)d_in[8];
    const float* bf1 = (const float*)d_in[9];
    const float* Wf2 = (const float*)d_in[10];
    const float* bf2 = (const float*)d_in[11];
    const float* Wf3 = (const float*)d_in[12];
    const float* bf3 = (const float*)d_in[13];
    float* out = (float*)d_out;

    char* p = (char*)d_ws;
    auto alloc = [&](size_t bytes) {
        void* r = (void*)p;
        p += (bytes + 255) & ~((size_t)255);
        return r;
    };
    int*   cnt    = (int*)  alloc(N_NODES * sizeof(int));
    int*   off    = (int*)  alloc((N_NODES + 1) * sizeof(int));
    int*   cursor = (int*)  alloc(N_NODES * sizeof(int));
    int*   bsum   = (int*)  alloc(SCAN_NB * sizeof(int));
    int*   bbase  = (int*)  alloc(SCAN_NB * sizeof(int));
    float* dinv   = (float*)alloc(N_NODES * sizeof(float));
    int2*  epack  = (int2*) alloc((size_t)N_EDGES * sizeof(int2));
    float* gb     = (float*)alloc(N_BUCKETS * 256 * sizeof(float));
    unsigned short* W1h = (unsigned short*)alloc(128 * 256 * 2);
    unsigned short* W1l = (unsigned short*)alloc(128 * 256 * 2);
    unsigned short* W2h = (unsigned short*)alloc(256 * 512 * 2);
    unsigned short* W2l = (unsigned short*)alloc(256 * 512 * 2);
    unsigned short* W3h = (unsigned short*)alloc(512 * 256 * 2);
    unsigned short* W3l = (unsigned short*)alloc(512 * 256 * 2);
    unsigned short* xb = (unsigned short*)alloc((size_t)N_NODES * 128 * 2);
    unsigned short* t0 = (unsigned short*)alloc((size_t)M_PAD * 128 * 2);
    unsigned short* h1 = (unsigned short*)alloc((size_t)N_NODES * 256 * 2);
    unsigned short* t1 = (unsigned short*)alloc((size_t)M_PAD * 256 * 2);
    unsigned short* h2 = (unsigned short*)alloc((size_t)M_PAD * 512 * 2);
    unsigned short* t2 = (unsigned short*)alloc((size_t)N_NODES * 256 * 2);

    const int* row = ei;
    const int* col = ei + N_EDGES;

    const int NB = (N_NODES + 255) / 256;  // 196
    const int EB = (N_EDGES + 255) / 256;

    // CSR build + norm (hierarchical scan)
    k_init<<<NB, 256, 0, stream>>>(cnt, gb);
    k_count<<<EB, 256, 0, stream>>>(col, cnt);
    k_scanA<<<SCAN_NB, 256, 0, stream>>>(cnt, bsum);
    k_scanB<<<1, 256, 0, stream>>>(bsum, bbase, off);
    k_scanC<<<SCAN_NB, 256, 0, stream>>>(cnt, bbase, off, cursor, dinv);
    k_fill<<<EB, 256, 0, stream>>>(row, col, dinv, cursor, epack);

    // weight prep (transpose + exact split) and x -> bf16
    k_prepW<<<(128 * 256 + 255) / 256, 256, 0, stream>>>(W1, W1h, W1l, 128, 256);
    k_prepW<<<(256 * 512 + 255) / 256, 256, 0, stream>>>(W2, W2h, W2l, 256, 512);
    k_prepW<<<(512 * 256 + 255) / 256, 256, 0, stream>>>(W3, W3h, W3l, 512, 256);
    k_prepX<<<(N_NODES * 128 + 255) / 256, 256, 0, stream>>>(x, xb);

    const int M = N_NODES;
    const int MB = (M + 127) / 128; // 391

    // conv1: t0 = agg(xb); h1 = relu(t0@W1 + b1)
    k_aggb<128, 0><<<N_NODES / 16, 256, 0, stream>>>(
        xb, off, epack, dinv, nullptr, t0, nullptr);
    {
        dim3 grid(MB, 256 / 128);
        k_gemm_b<1, 1><<<grid, 256, 0, stream>>>(t0, W1h, W1l, b1, h1, M, 128, 256);
    }
    // conv2: t1 = agg(h1); h2 = relu(t1@W2 + b2)
    k_aggb<256, 0><<<N_NODES / 8, 256, 0, stream>>>(
        h1, off, epack, dinv, nullptr, t1, nullptr);
    {
        dim3 grid(MB, 512 / 128);
        k_gemm_b<1, 1><<<grid, 256, 0, stream>>>(t1, W2h, W2l, b2, h2, M, 256, 512);
    }
    // conv3: t2 = h2@W3; fused agg + bias + relu + bucketed mean-pool
    {
        dim3 grid(MB, 256 / 128);
        k_gemm_b<0, 0><<<grid, 256, 0, stream>>>(h2, W3h, W3l, nullptr, t2, M, 512, 256);
    }
    k_aggb<256, 1><<<N_NODES / 8, 256, 0, stream>>>(
        t2, off, epack, dinv, b3, nullptr, gb);

    // MLP (reduces buckets internally)
    k_mlp<<<1, 256, 0, stream>>>(gb, Wf1, bf1, Wf2, bf2, Wf3, bf3, out);
}